// Round 16
// baseline (240.451 us; speedup 1.0000x reference)
//
#include <hip/hip_runtime.h>
#include <cstddef>
#include <cstdint>

#define BATCH 16
#define CHAN 3
#define HH 128
#define WW 128
#define PATCHK 7
#define HP 122                 // (128-7)/1 + 1
#define PDIM 147               // 3*7*7
#define NSAMP 4096
#define NPROJ 128
#define IMG_PIX (CHAN*HH*WW)   // 49152
#define TOT_PIX (BATCH*IMG_PIX)
#define COUNT_D ((double)BATCH*HP*HP*PDIM)   // 35007168

// ---------------- kernel A: weighted pixel sums (patch-tensor mean) -------
__global__ __launch_bounds__(256)
void k_wsum(const float* __restrict__ x, const float* __restrict__ y,
            double* __restrict__ outx, double* __restrict__ outy) {
  float sx = 0.f, sy = 0.f;
  const int stride = gridDim.x * blockDim.x;
  for (int e = blockIdx.x * blockDim.x + threadIdx.x; e < TOT_PIX; e += stride) {
    int j = e & (WW - 1);
    int i = (e >> 7) & (HH - 1);
    int wi = min(i, HP - 1) - max(0, i - (PATCHK - 1)) + 1;
    int wj = min(j, HP - 1) - max(0, j - (PATCHK - 1)) + 1;
    float w = (float)(wi * wj);
    sx = fmaf(x[e], w, sx);
    sy = fmaf(y[e], w, sy);
  }
  __shared__ float rx[256], ry[256];
  const int tid = threadIdx.x;
  rx[tid] = sx; ry[tid] = sy;
  __syncthreads();
  for (int off = 128; off; off >>= 1) {
    if (tid < off) { rx[tid] += rx[tid + off]; ry[tid] += ry[tid + off]; }
    __syncthreads();
  }
  if (tid == 0) { outx[blockIdx.x] = (double)rx[0]; outy[blockIdx.x] = (double)ry[0]; }
}

// mean diff + proj column sums fused
__global__ void k_meandiff(const double* __restrict__ px, const double* __restrict__ py,
                           double* __restrict__ dmean,
                           const float* __restrict__ proj, float* __restrict__ sp) {
  const int tid = threadIdx.x;
  if (tid < NPROJ) {
    float s = 0.f;
    for (int d = 0; d < PDIM; ++d) s += proj[d * NPROJ + tid];
    sp[tid] = s;
  }
  __shared__ double sd[256];
  sd[tid] = px[tid] - py[tid];
  __syncthreads();
  for (int off = 128; off; off >>= 1) {
    if (tid < off) sd[tid] += sd[tid + off];
    __syncthreads();
  }
  if (tid == 0) dmean[0] = sd[0] / COUNT_D;
}

// ---------------- kernel B: gather + projection GEMM (R10/R11-proven) -----
#define TM 128
#define ASTR (TM + 2)          // 130 words
#define KROWS 74
#define MINK(v) ((v) < 146 ? (v) : 146)

#define LB(dst, kk) _Pragma("unroll") \
  for (int pp = 0; pp < 16; ++pp) dst[pp] = bpr[(kk) * NPROJ + pp];

#define FMAK(kk, bb) { \
  const float2 a_ = *(const float2*)&As[(kk) * ASTR + lane * 2]; \
  _Pragma("unroll") \
  for (int pp = 0; pp < 16; ++pp) { \
    acc0[pp] = fmaf(a_.x, bb[pp], acc0[pp]); \
    acc1[pp] = fmaf(a_.y, bb[pp], acc1[pp]); } }

__global__ __launch_bounds__(512, 8)
void k_proj(const float* __restrict__ x, const float* __restrict__ y,
            const float* __restrict__ proj,
            const int* __restrict__ idx_x, const int* __restrict__ idx_y,
            float* __restrict__ PX, float* __restrict__ PY) {
  __shared__ float As[KROWS * ASTR];   // 38480 B
  __shared__ int offd[PDIM];
  __shared__ int basen[TM];

  const int z = blockIdx.z;
  const float* im = z ? y : x;
  const int* idx = z ? idx_y : idx_x;
  float* dst = z ? PY : PX;
  const int b = blockIdx.y;
  const int nbase = blockIdx.x * TM;
  const int tid = threadIdx.x;

  if (tid < PDIM) {                        // d = c*49 + kh*7 + kw
    int c = tid / 49, r = tid - c * 49, kh = r / 7, kw = r - kh * 7;
    offd[tid] = (c * HH + kh) * WW + kw;
  }
  if (tid >= 256 && tid < 256 + TM) {
    int n = tid - 256;
    int l = idx[nbase + n];
    int h0 = l / HP;
    basen[n] = h0 * WW + (l - h0 * HP);
  }
  __syncthreads();

  const float* imb = im + b * IMG_PIX;
  const int lane = tid & 63;
  const int w = __builtin_amdgcn_readfirstlane(tid >> 6);   // wave id -> SGPR
  const float* bpr = proj + w * 16;

  float acc0[16], acc1[16];
#pragma unroll
  for (int pp = 0; pp < 16; ++pp) { acc0[pp] = 0.f; acc1[pp] = 0.f; }

#pragma unroll 1
  for (int ph = 0; ph < 2; ++ph) {
    const int k0 = ph ? KROWS : 0;
    if (ph) __syncthreads();               // all reads of phase-1 As done

    for (int e = tid; e < KROWS * TM; e += 512) {
      int n = e / KROWS;
      int dr = e - n * KROWS;              // row within phase
      int d = dr + k0;                     // absolute patch-dim
      As[dr * ASTR + n] = (d < PDIM) ? imb[basen[n] + offd[d]] : 0.f;
    }
    __syncthreads();

    float b0[16], b1[16], b2[16], b3[16];
    LB(b0, k0); LB(b1, k0 + 1); LB(b2, k0 + 2);
    for (int kk = 0; kk < 72; kk += 4) {   // 18 iters, rows 0..71
      LB(b3, MINK(k0 + kk + 3));
      FMAK(kk, b0);
      LB(b0, MINK(k0 + kk + 4));
      FMAK(kk + 1, b1);
      LB(b1, MINK(k0 + kk + 5));
      FMAK(kk + 2, b2);
      LB(b2, MINK(k0 + kk + 6));
      FMAK(kk + 3, b3);
    }
    FMAK(72, b0);                          // rows 72,73 (phase-2 row 73 = 0)
    FMAK(73, b1);
  }

#pragma unroll
  for (int pp = 0; pp < 16; ++pp) {
    float* o = dst + (size_t)(b * NPROJ + w * 16 + pp) * NSAMP + nbase + lane * 2;
    *(float2*)o = make_float2(acc0[pp], acc1[pp]);
  }
}

// ---------------- kernel C: VT=32 sign-flip bitonic sort + |diff| ---------
// 2 waves (128 thr) per (b,p) pair. Element i = rh*1024 + w*512 + l*8 + rl:
// j in {1,2,4} -> rl registers; {8..256} -> lane exchange (dl=j/8, proven
// primitives: DPP quad_perm dl 1,2; ds_swizzle 4,8,16; shfl_xor 32);
// {512} -> warp LDS stage (16KB float4 buffer, XOR-swizzled slots);
// {1024,2048} -> rh registers (compile-time). Flip-domain masks: lane Gray
// d8..d128; d256 = (l>>5)^w; d512 = w ^ ct(rh&1); d1024/d2048 compile-time.
// permlane/row_ror remain banned (R5/R6 failures).
#define SIGNB 0x80000000u
__device__ __forceinline__ float xorf(float v, unsigned m) {
  return __int_as_float(__float_as_int(v) ^ (int)m);
}
#define CSW(a, b) { float _t = fminf(a, b); b = fmaxf(a, b); a = _t; }

#define SORT8A(v) do { \
  CSW(v[0],v[1]); CSW(v[3],v[2]); CSW(v[4],v[5]); CSW(v[7],v[6]); \
  CSW(v[0],v[2]); CSW(v[1],v[3]); CSW(v[6],v[4]); CSW(v[7],v[5]); \
  CSW(v[0],v[1]); CSW(v[2],v[3]); CSW(v[5],v[4]); CSW(v[7],v[6]); \
  CSW(v[0],v[4]); CSW(v[1],v[5]); CSW(v[2],v[6]); CSW(v[3],v[7]); \
  CSW(v[0],v[2]); CSW(v[1],v[3]); CSW(v[4],v[6]); CSW(v[5],v[7]); \
  CSW(v[0],v[1]); CSW(v[2],v[3]); CSW(v[4],v[5]); CSW(v[6],v[7]); } while (0)

#define REG3A(v) do { \
  CSW(v[0],v[4]); CSW(v[1],v[5]); CSW(v[2],v[6]); CSW(v[3],v[7]); \
  CSW(v[0],v[2]); CSW(v[1],v[3]); CSW(v[4],v[6]); CSW(v[5],v[7]); \
  CSW(v[0],v[1]); CSW(v[2],v[3]); CSW(v[4],v[5]); CSW(v[6],v[7]); } while (0)

#define FLIP8(v, m) { v[0]=xorf(v[0],m); v[1]=xorf(v[1],m); v[2]=xorf(v[2],m); \
  v[3]=xorf(v[3],m); v[4]=xorf(v[4],m); v[5]=xorf(v[5],m); v[6]=xorf(v[6],m); \
  v[7]=xorf(v[7],m); }

template <int DL>
__device__ __forceinline__ float swzxor(float v) {
  if constexpr (DL == 1) {        // DPP quad_perm [1,0,3,2] -> lane^1 (proven R9)
    return __int_as_float(
        __builtin_amdgcn_mov_dpp(__float_as_int(v), 0xB1, 0xF, 0xF, true));
  } else if constexpr (DL == 2) { // DPP quad_perm [2,3,0,1] -> lane^2 (proven R9)
    return __int_as_float(
        __builtin_amdgcn_mov_dpp(__float_as_int(v), 0x4E, 0xF, 0xF, true));
  } else if constexpr (DL <= 16) { // ds_swizzle bit-mode (proven R4)
    return __int_as_float(
        __builtin_amdgcn_ds_swizzle(__float_as_int(v), (DL << 10) | 0x1F));
  } else {                        // DL == 32 (proven R4)
    return __shfl_xor(v, DL, 64);
  }
}

template <int DL>
__device__ __forceinline__ void shufxy(float (&vx)[8], float (&vy)[8], bool keepLo) {
#pragma unroll
  for (int r = 0; r < 8; ++r) {
    float ox = swzxor<DL>(vx[r]);
    vx[r] = keepLo ? fminf(vx[r], ox) : fmaxf(vx[r], ox);
    float oy = swzxor<DL>(vy[r]);
    vy[r] = keepLo ? fminf(vy[r], oy) : fmaxf(vy[r], oy);
  }
}

// warp-crossing stage (j=512): exchange all 32 values with thread tid^64.
// XOR-swizzled float4 slots: slot (g*2+h)^(l&7) -> 8 lanes per bank-group
// (optimal for b128). Partner has same lane bits -> same swizzle.
__device__ __forceinline__ void wstage(float (&v)[4][8], float4* buf4,
                                       int tid, int sw, bool keep) {
  float4* wp = buf4 + tid * 8;
#pragma unroll
  for (int g = 0; g < 4; ++g) {
    wp[(g * 2) ^ sw]     = make_float4(v[g][0], v[g][1], v[g][2], v[g][3]);
    wp[(g * 2 + 1) ^ sw] = make_float4(v[g][4], v[g][5], v[g][6], v[g][7]);
  }
  __syncthreads();
  const float4* rp = buf4 + (tid ^ 64) * 8;
#pragma unroll
  for (int g = 0; g < 4; ++g) {
    float4 o0 = rp[(g * 2) ^ sw];
    float4 o1 = rp[(g * 2 + 1) ^ sw];
    v[g][0] = keep ? fminf(v[g][0], o0.x) : fmaxf(v[g][0], o0.x);
    v[g][1] = keep ? fminf(v[g][1], o0.y) : fmaxf(v[g][1], o0.y);
    v[g][2] = keep ? fminf(v[g][2], o0.z) : fmaxf(v[g][2], o0.z);
    v[g][3] = keep ? fminf(v[g][3], o0.w) : fmaxf(v[g][3], o0.w);
    v[g][4] = keep ? fminf(v[g][4], o1.x) : fmaxf(v[g][4], o1.x);
    v[g][5] = keep ? fminf(v[g][5], o1.y) : fmaxf(v[g][5], o1.y);
    v[g][6] = keep ? fminf(v[g][6], o1.z) : fmaxf(v[g][6], o1.z);
    v[g][7] = keep ? fminf(v[g][7], o1.w) : fmaxf(v[g][7], o1.w);
  }
  __syncthreads();
}

#define FLIPALL(m) { FLIP8(vx[0], m); FLIP8(vx[1], m); FLIP8(vx[2], m); FLIP8(vx[3], m); \
                     FLIP8(vy[0], m); FLIP8(vy[1], m); FLIP8(vy[2], m); FLIP8(vy[3], m); }
#define FLIP4G(m0, m1, m2, m3) { \
  FLIP8(vx[0], m0); FLIP8(vx[1], m1); FLIP8(vx[2], m2); FLIP8(vx[3], m3); \
  FLIP8(vy[0], m0); FLIP8(vy[1], m1); FLIP8(vy[2], m2); FLIP8(vy[3], m3); }
#define SHUFALL(DL, KP) { shufxy<DL>(vx[0], vy[0], KP); shufxy<DL>(vx[1], vy[1], KP); \
                          shufxy<DL>(vx[2], vy[2], KP); shufxy<DL>(vx[3], vy[3], KP); }
#define REG3ALL() { REG3A(vx[0]); REG3A(vx[1]); REG3A(vx[2]); REG3A(vx[3]); \
                    REG3A(vy[0]); REG3A(vy[1]); REG3A(vy[2]); REG3A(vy[3]); }
#define REGJ1(v) { _Pragma("unroll") \
  for (int r = 0; r < 8; ++r) { CSW(v[0][r], v[1][r]); CSW(v[2][r], v[3][r]); } }
#define REGJ2(v) { _Pragma("unroll") \
  for (int r = 0; r < 8; ++r) { CSW(v[0][r], v[2][r]); CSW(v[1][r], v[3][r]); } }

__global__ __launch_bounds__(128, 4)
void k_sortdiff(const float* __restrict__ PX, const float* __restrict__ PY,
                const float* __restrict__ sp, const double* __restrict__ dmean,
                float* __restrict__ bsum) {
  __shared__ float4 buf4[1024];      // 16 KB warp-exchange buffer
  __shared__ float red[2];
  const int bp = blockIdx.x;          // b*128 + p
  const int p = bp & (NPROJ - 1);
  const int tid = threadIdx.x;
  const int l = tid & 63;
  const int w = tid >> 6;
  const int sw = l & 7;

  float vx[4][8], vy[4][8];
  {
    const float4* rx = (const float4*)(PX + (size_t)bp * NSAMP + w * 512 + l * 8);
    const float4* ry = (const float4*)(PY + (size_t)bp * NSAMP + w * 512 + l * 8);
#pragma unroll
    for (int g = 0; g < 4; ++g) {
      float4 a0 = rx[g * 256], a1 = rx[g * 256 + 1];
      vx[g][0]=a0.x; vx[g][1]=a0.y; vx[g][2]=a0.z; vx[g][3]=a0.w;
      vx[g][4]=a1.x; vx[g][5]=a1.y; vx[g][6]=a1.z; vx[g][7]=a1.w;
      float4 b0 = ry[g * 256], b1 = ry[g * 256 + 1];
      vy[g][0]=b0.x; vy[g][1]=b0.y; vy[g][2]=b0.z; vy[g][3]=b0.w;
      vy[g][4]=b1.x; vy[g][5]=b1.y; vy[g][6]=b1.z; vy[g][7]=b1.w;
    }
  }

  const unsigned gl  = (unsigned)(l ^ (l >> 1));
  const unsigned mA   = (unsigned)(l & 1) << 31;           // m_8
  const unsigned d8   = (gl & 1u)  << 31;
  const unsigned d16  = (gl & 2u)  << 30;
  const unsigned d32  = (gl & 4u)  << 29;
  const unsigned d64  = (gl & 8u)  << 28;
  const unsigned d128 = (gl & 16u) << 27;
  const unsigned d256 = (unsigned)(((l >> 5) ^ w) & 1) << 31;
  const unsigned dW   = (unsigned)w << 31;
  const bool c1 = (l & 1) == 0, c2 = (l & 2) == 0, c4 = (l & 4) == 0;
  const bool c8 = (l & 8) == 0, c16 = (l & 16) == 0, c32 = (l & 32) == 0;
  const bool cW = (w == 0);

  // K=2..8: full 8-sorts in m_8 flip domain
  FLIPALL(mA);
  SORT8A(vx[0]); SORT8A(vx[1]); SORT8A(vx[2]); SORT8A(vx[3]);
  SORT8A(vy[0]); SORT8A(vy[1]); SORT8A(vy[2]); SORT8A(vy[3]);
  FLIPALL(d8);
  // K=16
  SHUFALL(1, c1); REG3ALL(); FLIPALL(d16);
  // K=32
  SHUFALL(2, c2); SHUFALL(1, c1); REG3ALL(); FLIPALL(d32);
  // K=64
  SHUFALL(4, c4); SHUFALL(2, c2); SHUFALL(1, c1); REG3ALL(); FLIPALL(d64);
  // K=128
  SHUFALL(8, c8); SHUFALL(4, c4); SHUFALL(2, c2); SHUFALL(1, c1);
  REG3ALL(); FLIPALL(d128);
  // K=256
  SHUFALL(16, c16); SHUFALL(8, c8); SHUFALL(4, c4); SHUFALL(2, c2);
  SHUFALL(1, c1); REG3ALL(); FLIPALL(d256);
  // K=512
  SHUFALL(32, c32); SHUFALL(16, c16); SHUFALL(8, c8); SHUFALL(4, c4);
  SHUFALL(2, c2); SHUFALL(1, c1); REG3ALL();
  FLIP4G(dW, dW ^ SIGNB, dW, dW ^ SIGNB);            // d512 = w ^ (rh&1)
  // K=1024: j=512 warp, then in-wave/reg
  wstage(vx, buf4, tid, sw, cW); wstage(vy, buf4, tid, sw, cW);
  SHUFALL(32, c32); SHUFALL(16, c16); SHUFALL(8, c8); SHUFALL(4, c4);
  SHUFALL(2, c2); SHUFALL(1, c1); REG3ALL();
  FLIP4G(0u, SIGNB, SIGNB, 0u);                      // d1024 = rh0 ^ rh1
  // K=2048: j=1024 reg, j=512 warp, rest
  REGJ1(vx); REGJ1(vy);
  wstage(vx, buf4, tid, sw, cW); wstage(vy, buf4, tid, sw, cW);
  SHUFALL(32, c32); SHUFALL(16, c16); SHUFALL(8, c8); SHUFALL(4, c4);
  SHUFALL(2, c2); SHUFALL(1, c1); REG3ALL();
  FLIP4G(0u, 0u, SIGNB, SIGNB);                      // d2048 = rh1
  // K=4096 (final, real domain): j=2048,1024 reg, j=512 warp, rest
  REGJ2(vx); REGJ2(vy); REGJ1(vx); REGJ1(vy);
  wstage(vx, buf4, tid, sw, cW); wstage(vy, buf4, tid, sw, cW);
  SHUFALL(32, c32); SHUFALL(16, c16); SHUFALL(8, c8); SHUFALL(4, c4);
  SHUFALL(2, c2); SHUFALL(1, c1); REG3ALL();

  // diff + reduce (register-local: vx/vy share element indices)
  const float delta = (float)(dmean[0]) * sp[p];
  float s = 0.f;
#pragma unroll
  for (int g = 0; g < 4; ++g)
#pragma unroll
    for (int r = 0; r < 8; ++r) s += fabsf(vx[g][r] - vy[g][r] - delta);

#pragma unroll
  for (int o = 1; o < 64; o <<= 1) s += __shfl_xor(s, o, 64);
  if (l == 0) red[w] = s;
  __syncthreads();
  if (tid == 0) bsum[bp] = red[0] + red[1];
}

// ---------------- kernel D: deterministic final reduce --------------------
__global__ void k_final(const float* __restrict__ bsum, float* __restrict__ out) {
  __shared__ double s[256];
  const int tid = threadIdx.x;
  double v = 0.0;
  for (int q = tid; q < BATCH * NPROJ; q += 256) v += (double)bsum[q];
  s[tid] = v;
  __syncthreads();
  for (int off = 128; off; off >>= 1) {
    if (tid < off) s[tid] += s[tid + off];
    __syncthreads();
  }
  if (tid == 0) out[0] = (float)(s[0] / ((double)NSAMP * NPROJ * BATCH));
}

extern "C" void kernel_launch(void* const* d_in, const int* in_sizes, int n_in,
                              void* d_out, int out_size, void* d_ws, size_t ws_size,
                              hipStream_t stream) {
  const float* x    = (const float*)d_in[0];
  const float* y    = (const float*)d_in[1];
  const float* proj = (const float*)d_in[2];
  const int* idx_x  = (const int*)d_in[3];
  const int* idx_y  = (const int*)d_in[4];
  float* out = (float*)d_out;

  char* ws = (char*)d_ws;
  double* pAx   = (double*)(ws + 0);
  double* pAy   = (double*)(ws + 2048);
  double* dmean = (double*)(ws + 4096);
  float*  sp    = (float*)(ws + 4160);
  float*  bsum  = (float*)(ws + 8192);
  float*  PX    = (float*)(ws + 16384);
  float*  PY    = PX + (size_t)BATCH * NPROJ * NSAMP;

  const size_t need = 16384 + 2ull * BATCH * NPROJ * NSAMP * sizeof(float);
  if (ws_size < need) return;

  k_wsum    <<<256, 256, 0, stream>>>(x, y, pAx, pAy);
  k_meandiff<<<1, 256, 0, stream>>>(pAx, pAy, dmean, proj, sp);
  k_proj    <<<dim3(NSAMP / TM, BATCH, 2), 512, 0, stream>>>(x, y, proj, idx_x, idx_y, PX, PY);
  k_sortdiff<<<BATCH * NPROJ, 128, 0, stream>>>(PX, PY, sp, dmean, bsum);
  k_final   <<<1, 256, 0, stream>>>(bsum, out);
}

// Round 17
// 225.488 us; speedup vs baseline: 1.0664x; 1.0664x over previous
//
#include <hip/hip_runtime.h>
#include <cstddef>
#include <cstdint>

#define BATCH 16
#define CHAN 3
#define HH 128
#define WW 128
#define PATCHK 7
#define HP 122                 // (128-7)/1 + 1
#define PDIM 147               // 3*7*7
#define NSAMP 4096
#define NPROJ 128
#define IMG_PIX (CHAN*HH*WW)   // 49152
#define TOT_PIX (BATCH*IMG_PIX)
#define COUNT_D ((double)BATCH*HP*HP*PDIM)   // 35007168

// ---------------- kernel A: weighted pixel sums (patch-tensor mean) -------
__global__ __launch_bounds__(256)
void k_wsum(const float* __restrict__ x, const float* __restrict__ y,
            double* __restrict__ outx, double* __restrict__ outy) {
  float sx = 0.f, sy = 0.f;
  const int stride = gridDim.x * blockDim.x;
  for (int e = blockIdx.x * blockDim.x + threadIdx.x; e < TOT_PIX; e += stride) {
    int j = e & (WW - 1);
    int i = (e >> 7) & (HH - 1);
    int wi = min(i, HP - 1) - max(0, i - (PATCHK - 1)) + 1;
    int wj = min(j, HP - 1) - max(0, j - (PATCHK - 1)) + 1;
    float w = (float)(wi * wj);
    sx = fmaf(x[e], w, sx);
    sy = fmaf(y[e], w, sy);
  }
  __shared__ float rx[256], ry[256];
  const int tid = threadIdx.x;
  rx[tid] = sx; ry[tid] = sy;
  __syncthreads();
  for (int off = 128; off; off >>= 1) {
    if (tid < off) { rx[tid] += rx[tid + off]; ry[tid] += ry[tid + off]; }
    __syncthreads();
  }
  if (tid == 0) { outx[blockIdx.x] = (double)rx[0]; outy[blockIdx.x] = (double)ry[0]; }
}

// mean diff + proj column sums fused
__global__ void k_meandiff(const double* __restrict__ px, const double* __restrict__ py,
                           double* __restrict__ dmean,
                           const float* __restrict__ proj, float* __restrict__ sp) {
  const int tid = threadIdx.x;
  if (tid < NPROJ) {
    float s = 0.f;
    for (int d = 0; d < PDIM; ++d) s += proj[d * NPROJ + tid];
    sp[tid] = s;
  }
  __shared__ double sd[256];
  sd[tid] = px[tid] - py[tid];
  __syncthreads();
  for (int off = 128; off; off >>= 1) {
    if (tid < off) sd[tid] += sd[tid + off];
    __syncthreads();
  }
  if (tid == 0) dmean[0] = sd[0] / COUNT_D;
}

// ---------------- kernel B: gather + projection GEMM (R10/R11-proven) -----
#define TM 128
#define ASTR (TM + 2)          // 130 words
#define KROWS 74
#define MINK(v) ((v) < 146 ? (v) : 146)

#define LB(dst, kk) _Pragma("unroll") \
  for (int pp = 0; pp < 16; ++pp) dst[pp] = bpr[(kk) * NPROJ + pp];

#define FMAK(kk, bb) { \
  const float2 a_ = *(const float2*)&As[(kk) * ASTR + lane * 2]; \
  _Pragma("unroll") \
  for (int pp = 0; pp < 16; ++pp) { \
    acc0[pp] = fmaf(a_.x, bb[pp], acc0[pp]); \
    acc1[pp] = fmaf(a_.y, bb[pp], acc1[pp]); } }

__global__ __launch_bounds__(512, 8)
void k_proj(const float* __restrict__ x, const float* __restrict__ y,
            const float* __restrict__ proj,
            const int* __restrict__ idx_x, const int* __restrict__ idx_y,
            float* __restrict__ PX, float* __restrict__ PY) {
  __shared__ float As[KROWS * ASTR];   // 38480 B
  __shared__ int offd[PDIM];
  __shared__ int basen[TM];

  const int z = blockIdx.z;
  const float* im = z ? y : x;
  const int* idx = z ? idx_y : idx_x;
  float* dst = z ? PY : PX;
  const int b = blockIdx.y;
  const int nbase = blockIdx.x * TM;
  const int tid = threadIdx.x;

  if (tid < PDIM) {                        // d = c*49 + kh*7 + kw
    int c = tid / 49, r = tid - c * 49, kh = r / 7, kw = r - kh * 7;
    offd[tid] = (c * HH + kh) * WW + kw;
  }
  if (tid >= 256 && tid < 256 + TM) {
    int n = tid - 256;
    int l = idx[nbase + n];
    int h0 = l / HP;
    basen[n] = h0 * WW + (l - h0 * HP);
  }
  __syncthreads();

  const float* imb = im + b * IMG_PIX;
  const int lane = tid & 63;
  const int w = __builtin_amdgcn_readfirstlane(tid >> 6);   // wave id -> SGPR
  const float* bpr = proj + w * 16;

  float acc0[16], acc1[16];
#pragma unroll
  for (int pp = 0; pp < 16; ++pp) { acc0[pp] = 0.f; acc1[pp] = 0.f; }

#pragma unroll 1
  for (int ph = 0; ph < 2; ++ph) {
    const int k0 = ph ? KROWS : 0;
    if (ph) __syncthreads();               // all reads of phase-1 As done

    for (int e = tid; e < KROWS * TM; e += 512) {
      int n = e / KROWS;
      int dr = e - n * KROWS;              // row within phase
      int d = dr + k0;                     // absolute patch-dim
      As[dr * ASTR + n] = (d < PDIM) ? imb[basen[n] + offd[d]] : 0.f;
    }
    __syncthreads();

    float b0[16], b1[16], b2[16], b3[16];
    LB(b0, k0); LB(b1, k0 + 1); LB(b2, k0 + 2);
    for (int kk = 0; kk < 72; kk += 4) {   // 18 iters, rows 0..71
      LB(b3, MINK(k0 + kk + 3));
      FMAK(kk, b0);
      LB(b0, MINK(k0 + kk + 4));
      FMAK(kk + 1, b1);
      LB(b1, MINK(k0 + kk + 5));
      FMAK(kk + 2, b2);
      LB(b2, MINK(k0 + kk + 6));
      FMAK(kk + 3, b3);
    }
    FMAK(72, b0);                          // rows 72,73 (phase-2 row 73 = 0)
    FMAK(73, b1);
  }

#pragma unroll
  for (int pp = 0; pp < 16; ++pp) {
    float* o = dst + (size_t)(b * NPROJ + w * 16 + pp) * NSAMP + nbase + lane * 2;
    *(float2*)o = make_float2(acc0[pp], acc1[pp]);
  }
}

// ---------------- kernel C: sign-flip bitonic sort + |diff| ---------------
// R11-proven VT=8 structure. THIS ROUND'S ONLY CHANGE: DL=8 exchange via
// DPP row_ror:8 (0x128; rotate-by-8 within 16-lane row == lane^8, direction-
// independent). Isolated test: DL=1,2 quad_perm proven R9; DL=4,16 stay
// ds_swizzle; DL=32 stays shfl_xor. permlane stays banned.
__device__ __forceinline__ float xorf(float v, unsigned m) {
  return __int_as_float(__float_as_int(v) ^ (int)m);
}
#define CSW(a, b) { float _t = fminf(a, b); b = fmaxf(a, b); a = _t; }

#define SORT8A(v) do { \
  CSW(v[0],v[1]); CSW(v[3],v[2]); CSW(v[4],v[5]); CSW(v[7],v[6]); \
  CSW(v[0],v[2]); CSW(v[1],v[3]); CSW(v[6],v[4]); CSW(v[7],v[5]); \
  CSW(v[0],v[1]); CSW(v[2],v[3]); CSW(v[5],v[4]); CSW(v[7],v[6]); \
  CSW(v[0],v[4]); CSW(v[1],v[5]); CSW(v[2],v[6]); CSW(v[3],v[7]); \
  CSW(v[0],v[2]); CSW(v[1],v[3]); CSW(v[4],v[6]); CSW(v[5],v[7]); \
  CSW(v[0],v[1]); CSW(v[2],v[3]); CSW(v[4],v[5]); CSW(v[6],v[7]); } while (0)

#define REG3A(v) do { \
  CSW(v[0],v[4]); CSW(v[1],v[5]); CSW(v[2],v[6]); CSW(v[3],v[7]); \
  CSW(v[0],v[2]); CSW(v[1],v[3]); CSW(v[4],v[6]); CSW(v[5],v[7]); \
  CSW(v[0],v[1]); CSW(v[2],v[3]); CSW(v[4],v[5]); CSW(v[6],v[7]); } while (0)

#define FLIP8(v, m) { v[0]=xorf(v[0],m); v[1]=xorf(v[1],m); v[2]=xorf(v[2],m); \
  v[3]=xorf(v[3],m); v[4]=xorf(v[4],m); v[5]=xorf(v[5],m); v[6]=xorf(v[6],m); \
  v[7]=xorf(v[7],m); }

template <int DL>
__device__ __forceinline__ float swzxor(float v) {
  if constexpr (DL == 1) {        // DPP quad_perm [1,0,3,2] -> lane^1 (proven R9)
    return __int_as_float(
        __builtin_amdgcn_mov_dpp(__float_as_int(v), 0xB1, 0xF, 0xF, true));
  } else if constexpr (DL == 2) { // DPP quad_perm [2,3,0,1] -> lane^2 (proven R9)
    return __int_as_float(
        __builtin_amdgcn_mov_dpp(__float_as_int(v), 0x4E, 0xF, 0xF, true));
  } else if constexpr (DL == 8) { // DPP row_ror:8 -> lane^8 (UNDER TEST)
    return __int_as_float(
        __builtin_amdgcn_mov_dpp(__float_as_int(v), 0x128, 0xF, 0xF, true));
  } else if constexpr (DL <= 16) { // ds_swizzle bit-mode (proven R4): DL 4,16
    return __int_as_float(
        __builtin_amdgcn_ds_swizzle(__float_as_int(v), (DL << 10) | 0x1F));
  } else {                        // DL == 32 (proven R4)
    return __shfl_xor(v, DL, 64);
  }
}

template <int DL>
__device__ __forceinline__ void shufxy(float (&vx)[8], float (&vy)[8], bool keepLo) {
  float ox[8], oy[8];
#pragma unroll
  for (int r = 0; r < 8; ++r) { ox[r] = swzxor<DL>(vx[r]); oy[r] = swzxor<DL>(vy[r]); }
  if (keepLo) {
#pragma unroll
    for (int r = 0; r < 8; ++r) { vx[r] = fminf(vx[r], ox[r]); vy[r] = fminf(vy[r], oy[r]); }
  } else {
#pragma unroll
    for (int r = 0; r < 8; ++r) { vx[r] = fmaxf(vx[r], ox[r]); vy[r] = fmaxf(vy[r], oy[r]); }
  }
}

__device__ __forceinline__ void lds_stage(float (&vx)[8], float (&vy)[8],
                                          float* lx, float* ly, int t, int dl, bool kl) {
  ((float4*)lx)[t * 2]     = make_float4(vx[0], vx[1], vx[2], vx[3]);
  ((float4*)lx)[t * 2 + 1] = make_float4(vx[4], vx[5], vx[6], vx[7]);
  ((float4*)ly)[t * 2]     = make_float4(vy[0], vy[1], vy[2], vy[3]);
  ((float4*)ly)[t * 2 + 1] = make_float4(vy[4], vy[5], vy[6], vy[7]);
  __syncthreads();
  const int pt = (t ^ dl) * 2;
  float4 ox0 = ((const float4*)lx)[pt], ox1 = ((const float4*)lx)[pt + 1];
  float4 oy0 = ((const float4*)ly)[pt], oy1 = ((const float4*)ly)[pt + 1];
  if (kl) {
    vx[0] = fminf(vx[0], ox0.x); vx[1] = fminf(vx[1], ox0.y);
    vx[2] = fminf(vx[2], ox0.z); vx[3] = fminf(vx[3], ox0.w);
    vx[4] = fminf(vx[4], ox1.x); vx[5] = fminf(vx[5], ox1.y);
    vx[6] = fminf(vx[6], ox1.z); vx[7] = fminf(vx[7], ox1.w);
    vy[0] = fminf(vy[0], oy0.x); vy[1] = fminf(vy[1], oy0.y);
    vy[2] = fminf(vy[2], oy0.z); vy[3] = fminf(vy[3], oy0.w);
    vy[4] = fminf(vy[4], oy1.x); vy[5] = fminf(vy[5], oy1.y);
    vy[6] = fminf(vy[6], oy1.z); vy[7] = fminf(vy[7], oy1.w);
  } else {
    vx[0] = fmaxf(vx[0], ox0.x); vx[1] = fmaxf(vx[1], ox0.y);
    vx[2] = fmaxf(vx[2], ox0.z); vx[3] = fmaxf(vx[3], ox0.w);
    vx[4] = fmaxf(vx[4], ox1.x); vx[5] = fmaxf(vx[5], ox1.y);
    vx[6] = fmaxf(vx[6], ox1.z); vx[7] = fmaxf(vx[7], ox1.w);
    vy[0] = fmaxf(vy[0], oy0.x); vy[1] = fmaxf(vy[1], oy0.y);
    vy[2] = fmaxf(vy[2], oy0.z); vy[3] = fmaxf(vy[3], oy0.w);
    vy[4] = fmaxf(vy[4], oy1.x); vy[5] = fmaxf(vy[5], oy1.y);
    vy[6] = fmaxf(vy[6], oy1.z); vy[7] = fmaxf(vy[7], oy1.w);
  }
  __syncthreads();
}

__global__ __launch_bounds__(512)
void k_sortdiff(const float* __restrict__ PX, const float* __restrict__ PY,
                const float* __restrict__ sp, const double* __restrict__ dmean,
                float* __restrict__ bsum) {
  __shared__ float lx[NSAMP];
  __shared__ float ly[NSAMP];
  __shared__ float red[8];
  const int bp = blockIdx.x;          // b*128 + p
  const int p = bp & (NPROJ - 1);
  const unsigned t = threadIdx.x;

  const unsigned g = t ^ (t >> 1);
  const unsigned mA    = (t & 1u)   << 31;
  const unsigned dA16  = (g & 1u)   << 31;
  const unsigned d16   = (g & 2u)   << 30;
  const unsigned d32   = (g & 4u)   << 29;
  const unsigned d64   = (g & 8u)   << 28;
  const unsigned d128  = (g & 16u)  << 27;
  const unsigned d256  = (g & 32u)  << 26;
  const unsigned d512  = (g & 64u)  << 25;
  const unsigned d1024 = (g & 128u) << 24;
  const unsigned d2048 = (t & 256u) << 23;

  const bool k1  = (t & 1u)  == 0, k2  = (t & 2u)  == 0, k4 = (t & 4u) == 0;
  const bool k8  = (t & 8u)  == 0, k16 = (t & 16u) == 0, k32 = (t & 32u) == 0;
  const bool kl64 = (t & 64u) == 0, kl128 = (t & 128u) == 0, kl256 = (t & 256u) == 0;

  float vx[8], vy[8];
  {
    const float4* rx = (const float4*)(PX + (size_t)bp * NSAMP) + t * 2;
    const float4* ry = (const float4*)(PY + (size_t)bp * NSAMP) + t * 2;
    float4 x0 = rx[0], x1 = rx[1], y0 = ry[0], y1 = ry[1];
    vx[0]=x0.x; vx[1]=x0.y; vx[2]=x0.z; vx[3]=x0.w;
    vx[4]=x1.x; vx[5]=x1.y; vx[6]=x1.z; vx[7]=x1.w;
    vy[0]=y0.x; vy[1]=y0.y; vy[2]=y0.z; vy[3]=y0.w;
    vy[4]=y1.x; vy[5]=y1.y; vy[6]=y1.z; vy[7]=y1.w;
  }

  FLIP8(vx, mA); FLIP8(vy, mA);
  SORT8A(vx); SORT8A(vy);
  FLIP8(vx, dA16); FLIP8(vy, dA16);

  // K=16
  shufxy<1>(vx, vy, k1); REG3A(vx); REG3A(vy);
  FLIP8(vx, d16); FLIP8(vy, d16);
  // K=32
  shufxy<2>(vx, vy, k2); shufxy<1>(vx, vy, k1); REG3A(vx); REG3A(vy);
  FLIP8(vx, d32); FLIP8(vy, d32);
  // K=64
  shufxy<4>(vx, vy, k4); shufxy<2>(vx, vy, k2); shufxy<1>(vx, vy, k1);
  REG3A(vx); REG3A(vy);
  FLIP8(vx, d64); FLIP8(vy, d64);
  // K=128
  shufxy<8>(vx, vy, k8); shufxy<4>(vx, vy, k4); shufxy<2>(vx, vy, k2);
  shufxy<1>(vx, vy, k1); REG3A(vx); REG3A(vy);
  FLIP8(vx, d128); FLIP8(vy, d128);
  // K=256
  shufxy<16>(vx, vy, k16); shufxy<8>(vx, vy, k8); shufxy<4>(vx, vy, k4);
  shufxy<2>(vx, vy, k2); shufxy<1>(vx, vy, k1); REG3A(vx); REG3A(vy);
  FLIP8(vx, d256); FLIP8(vy, d256);
  // K=512
  shufxy<32>(vx, vy, k32); shufxy<16>(vx, vy, k16); shufxy<8>(vx, vy, k8);
  shufxy<4>(vx, vy, k4); shufxy<2>(vx, vy, k2); shufxy<1>(vx, vy, k1);
  REG3A(vx); REG3A(vy);
  FLIP8(vx, d512); FLIP8(vy, d512);
  // K=1024
  lds_stage(vx, vy, lx, ly, (int)t, 64, kl64);
  shufxy<32>(vx, vy, k32); shufxy<16>(vx, vy, k16); shufxy<8>(vx, vy, k8);
  shufxy<4>(vx, vy, k4); shufxy<2>(vx, vy, k2); shufxy<1>(vx, vy, k1);
  REG3A(vx); REG3A(vy);
  FLIP8(vx, d1024); FLIP8(vy, d1024);
  // K=2048
  lds_stage(vx, vy, lx, ly, (int)t, 128, kl128);
  lds_stage(vx, vy, lx, ly, (int)t, 64, kl64);
  shufxy<32>(vx, vy, k32); shufxy<16>(vx, vy, k16); shufxy<8>(vx, vy, k8);
  shufxy<4>(vx, vy, k4); shufxy<2>(vx, vy, k2); shufxy<1>(vx, vy, k1);
  REG3A(vx); REG3A(vy);
  FLIP8(vx, d2048); FLIP8(vy, d2048);
  // K=4096 (final, real domain, ascending)
  lds_stage(vx, vy, lx, ly, (int)t, 256, kl256);
  lds_stage(vx, vy, lx, ly, (int)t, 128, kl128);
  lds_stage(vx, vy, lx, ly, (int)t, 64, kl64);
  shufxy<32>(vx, vy, k32); shufxy<16>(vx, vy, k16); shufxy<8>(vx, vy, k8);
  shufxy<4>(vx, vy, k4); shufxy<2>(vx, vy, k2); shufxy<1>(vx, vy, k1);
  REG3A(vx); REG3A(vy);

  const float delta = (float)(dmean[0]) * sp[p];
  float s = 0.f;
#pragma unroll
  for (int r = 0; r < 8; ++r) s += fabsf(vx[r] - vy[r] - delta);

#pragma unroll
  for (int o = 1; o < 64; o <<= 1) s += __shfl_xor(s, o, 64);
  if ((t & 63u) == 0) red[t >> 6] = s;
  __syncthreads();
  if (t == 0) {
    float tot = 0.f;
#pragma unroll
    for (int i = 0; i < 8; ++i) tot += red[i];
    bsum[bp] = tot;
  }
}

// ---------------- kernel D: deterministic final reduce --------------------
__global__ void k_final(const float* __restrict__ bsum, float* __restrict__ out) {
  __shared__ double s[256];
  const int tid = threadIdx.x;
  double v = 0.0;
  for (int q = tid; q < BATCH * NPROJ; q += 256) v += (double)bsum[q];
  s[tid] = v;
  __syncthreads();
  for (int off = 128; off; off >>= 1) {
    if (tid < off) s[tid] += s[tid + off];
    __syncthreads();
  }
  if (tid == 0) out[0] = (float)(s[0] / ((double)NSAMP * NPROJ * BATCH));
}

extern "C" void kernel_launch(void* const* d_in, const int* in_sizes, int n_in,
                              void* d_out, int out_size, void* d_ws, size_t ws_size,
                              hipStream_t stream) {
  const float* x    = (const float*)d_in[0];
  const float* y    = (const float*)d_in[1];
  const float* proj = (const float*)d_in[2];
  const int* idx_x  = (const int*)d_in[3];
  const int* idx_y  = (const int*)d_in[4];
  float* out = (float*)d_out;

  char* ws = (char*)d_ws;
  double* pAx   = (double*)(ws + 0);
  double* pAy   = (double*)(ws + 2048);
  double* dmean = (double*)(ws + 4096);
  float*  sp    = (float*)(ws + 4160);
  float*  bsum  = (float*)(ws + 8192);
  float*  PX    = (float*)(ws + 16384);
  float*  PY    = PX + (size_t)BATCH * NPROJ * NSAMP;

  const size_t need = 16384 + 2ull * BATCH * NPROJ * NSAMP * sizeof(float);
  if (ws_size < need) return;

  k_wsum    <<<256, 256, 0, stream>>>(x, y, pAx, pAy);
  k_meandiff<<<1, 256, 0, stream>>>(pAx, pAy, dmean, proj, sp);
  k_proj    <<<dim3(NSAMP / TM, BATCH, 2), 512, 0, stream>>>(x, y, proj, idx_x, idx_y, PX, PY);
  k_sortdiff<<<BATCH * NPROJ, 512, 0, stream>>>(PX, PY, sp, dmean, bsum);
  k_final   <<<1, 256, 0, stream>>>(bsum, out);
}